// Round 1
// baseline (8410.691 us; speedup 1.0000x reference)
//
#include <hip/hip_runtime.h>
#include <hip/hip_bf16.h>

// ViT forward, MI355X gfx950. Round 0: correctness-first bf16-MFMA implementation.
// Residual stream h kept fp32; all GEMMs bf16-in/fp32-acc via mfma_f32_16x16x32_bf16.

typedef __bf16 bf16;
typedef __bf16 bf16x8 __attribute__((ext_vector_type(8)));
typedef float  f32x4  __attribute__((ext_vector_type(4)));

static __device__ __forceinline__ f32x4 mfma_bf16(bf16x8 a, bf16x8 b, f32x4 c) {
  return __builtin_amdgcn_mfma_f32_16x16x32_bf16(a, b, c, 0, 0, 0);
}

// ---------------- small setup kernels ----------------

__global__ __launch_bounds__(256) void f2b_k(const float* __restrict__ a, bf16* __restrict__ o, int n) {
  int i = blockIdx.x * 256 + threadIdx.x;
  if (i < n) o[i] = (bf16)a[i];
}

__global__ __launch_bounds__(256) void posenc_k(float* __restrict__ pos) {
  int l = blockIdx.x;
  for (int d = threadIdx.x; d < 768; d += 256) {
    int ieff = d & ~1;
    float ang = (float)l * expf(-(float)ieff * (9.210340371976184f / 768.0f)); // 10000^{-i/768}
    pos[l * 768 + d] = (d & 1) ? cosf(ang) : sinf(ang);
  }
}

// patches[t, c*256+i*16+j] = x[b, c, ph*16+i, pw*16+j],  t = b*196 + ph*14 + pw
__global__ __launch_bounds__(256) void patchify_k(const float* __restrict__ x, bf16* __restrict__ p) {
  int idx = blockIdx.x * 256 + threadIdx.x;     // 6272*768 exact
  int t = idx / 768, col = idx - t * 768;
  int b = t / 196, pp = t - b * 196;
  int ph = pp / 14, pw = pp - ph * 14;
  int c = col >> 8, r = col & 255, i = r >> 4, j = r & 15;
  p[idx] = (bf16)x[((b * 3 + c) * 224 + ph * 16 + i) * 224 + pw * 16 + j];
}

// h rows l>=1 already hold emb (from proj GEMM); add pos; row l==0 := cls + pos[0]
__global__ __launch_bounds__(256) void combine_k(float* __restrict__ h, const float* __restrict__ pos,
                                                 const float* __restrict__ cls) {
  int idx = blockIdx.x * 256 + threadIdx.x;     // 6304*768 exact
  int t = idx / 768, d = idx - t * 768;
  int l = t % 197;
  float p = pos[l * 768 + d];
  if (l == 0) h[idx] = cls[d] + p;
  else        h[idx] += p;
}

// LayerNorm over 768. OBF=1: bf16 out (stride 768). OBF=0: fp32 out (stride 768).
// Input row = blockIdx.x * instride (instride in elements).
template<int OBF>
__global__ __launch_bounds__(256) void ln_k(const float* __restrict__ x, const float* __restrict__ g,
                                            const float* __restrict__ bb, void* __restrict__ yv,
                                            int instride) {
  int row = blockIdx.x;
  const float* xr = x + (size_t)row * instride;
  int tid = threadIdx.x;
  float v0 = xr[tid], v1 = xr[tid + 256], v2 = xr[tid + 512];
  float s = v0 + v1 + v2, s2 = v0 * v0 + v1 * v1 + v2 * v2;
  #pragma unroll
  for (int o = 1; o < 64; o <<= 1) { s += __shfl_xor(s, o); s2 += __shfl_xor(s2, o); }
  __shared__ float red[8];
  if ((tid & 63) == 0) { red[tid >> 6] = s; red[4 + (tid >> 6)] = s2; }
  __syncthreads();
  float S = red[0] + red[1] + red[2] + red[3];
  float S2 = red[4] + red[5] + red[6] + red[7];
  float m = S * (1.0f / 768.0f);
  float inv = rsqrtf(S2 * (1.0f / 768.0f) - m * m + 1e-5f);
  if constexpr (OBF) {
    bf16* yr = (bf16*)yv + (size_t)row * 768;
    yr[tid]       = (bf16)((v0 - m) * inv * g[tid]       + bb[tid]);
    yr[tid + 256] = (bf16)((v1 - m) * inv * g[tid + 256] + bb[tid + 256]);
    yr[tid + 512] = (bf16)((v2 - m) * inv * g[tid + 512] + bb[tid + 512]);
  } else {
    float* yr = (float*)yv + (size_t)row * 768;
    yr[tid]       = (v0 - m) * inv * g[tid]       + bb[tid];
    yr[tid + 256] = (v1 - m) * inv * g[tid + 256] + bb[tid + 256];
    yr[tid + 512] = (v2 - m) * inv * g[tid + 512] + bb[tid + 512];
  }
}

// ---------------- NT GEMM: C[M,N] = A[M,K] * B[N,K]^T + bias ----------------
// 128x128 tile, BK=64, 4 waves (2x2 of 64x64), mfma 16x16x32 bf16.
// EPI: 0=PROJ (write h with row remap t -> b*197+1+p)
//      1=QKV  (scatter to Q/K/Vt per non-standard head split; Q *= 0.125)
//      2=ACCUM (outF[t*768+col] += val)     [O-proj, FC2]
//      3=FC1  (exact gelu -> bf16 outB stride 3072)
template<int EPI>
__global__ __launch_bounds__(256) void gemm_nt(
    const bf16* __restrict__ A, const bf16* __restrict__ B,
    int M, int N, int K, const float* __restrict__ bias,
    float* __restrict__ outF, bf16* __restrict__ outB,
    bf16* __restrict__ outQ, bf16* __restrict__ outK, bf16* __restrict__ outV)
{
  __shared__ alignas(16) bf16 As[128 * 72];   // [128][64] pad to 72 (2-way max on b128 reads)
  __shared__ alignas(16) bf16 Bs[128 * 72];
  const int tid = threadIdx.x;
  const int lane = tid & 63, wave = tid >> 6;
  const int wr = wave >> 1, wc = wave & 1;
  const int lrow = lane & 15, lgrp = lane >> 4;
  const int row0 = blockIdx.x * 128, col0 = blockIdx.y * 128;

  f32x4 acc[4][4] = {};
  uint4 ra[4], rb[4];
  const int sr = tid >> 3;          // staging: 128 rows x 8 chunks of 8 bf16
  const int sc = (tid & 7) << 3;

  const bf16* Agb = A + (size_t)row0 * K;
  const bf16* Bgb = B + (size_t)col0 * K;

  #pragma unroll
  for (int i = 0; i < 4; ++i) {
    ra[i] = *(const uint4*)(Agb + (size_t)(i * 32 + sr) * K + sc);
    rb[i] = *(const uint4*)(Bgb + (size_t)(i * 32 + sr) * K + sc);
  }
  const int nk = K >> 6;
  for (int kt = 0; kt < nk; ++kt) {
    if (kt) __syncthreads();
    #pragma unroll
    for (int i = 0; i < 4; ++i) {
      *(uint4*)(As + (i * 32 + sr) * 72 + sc) = ra[i];
      *(uint4*)(Bs + (i * 32 + sr) * 72 + sc) = rb[i];
    }
    __syncthreads();
    if (kt + 1 < nk) {
      const bf16* Ag = Agb + (kt + 1) * 64;
      const bf16* Bg = Bgb + (kt + 1) * 64;
      #pragma unroll
      for (int i = 0; i < 4; ++i) {
        ra[i] = *(const uint4*)(Ag + (size_t)(i * 32 + sr) * K + sc);
        rb[i] = *(const uint4*)(Bg + (size_t)(i * 32 + sr) * K + sc);
      }
    }
    #pragma unroll
    for (int kk = 0; kk < 2; ++kk) {
      bf16x8 af[4], bfr[4];
      #pragma unroll
      for (int mi = 0; mi < 4; ++mi)
        af[mi] = *(const bf16x8*)(As + (wr * 64 + mi * 16 + lrow) * 72 + kk * 32 + (lgrp << 3));
      #pragma unroll
      for (int ni = 0; ni < 4; ++ni)
        bfr[ni] = *(const bf16x8*)(Bs + (wc * 64 + ni * 16 + lrow) * 72 + kk * 32 + (lgrp << 3));
      #pragma unroll
      for (int mi = 0; mi < 4; ++mi)
        #pragma unroll
        for (int ni = 0; ni < 4; ++ni)
          acc[mi][ni] = mfma_bf16(af[mi], bfr[ni], acc[mi][ni]);
    }
  }

  // epilogue: C frag layout (verified m89): col = lane&15, row = (lane>>4)*4 + j
  #pragma unroll
  for (int ni = 0; ni < 4; ++ni) {
    const int col = col0 + wc * 64 + ni * 16 + lrow;
    const float bs = bias[col];
    int comp = 0, dd = 0, hh = 0;
    if (EPI == 1) { comp = col / 768; int rem = col - comp * 768; dd = rem / 12; hh = rem - dd * 12; }
    #pragma unroll
    for (int mi = 0; mi < 4; ++mi) {
      const int rbase = row0 + wr * 64 + mi * 16 + (lgrp << 2);
      #pragma unroll
      for (int j = 0; j < 4; ++j) {
        const int t = rbase + j;
        if (t >= M) continue;
        float val = acc[mi][ni][j] + bs;
        if (EPI == 0) {
          int b = t / 196, p = t - b * 196;
          outF[((size_t)(b * 197 + 1 + p)) * 768 + col] = val;
        } else if (EPI == 1) {
          int b = t / 197, l = t - b * 197;
          if (comp == 0)      outQ[(((size_t)(b * 12 + hh)) * 208 + l) * 64 + dd] = (bf16)(val * 0.125f);
          else if (comp == 1) outK[(((size_t)(b * 12 + hh)) * 208 + l) * 64 + dd] = (bf16)val;
          else                outV[(((size_t)(b * 12 + hh)) * 64 + dd) * 208 + l] = (bf16)val;
        } else if (EPI == 2) {
          outF[(size_t)t * 768 + col] += val;
        } else {
          outB[(size_t)t * 3072 + col] = (bf16)(0.5f * val * (1.0f + erff(val * 0.70710678118654752f)));
        }
      }
    }
  }
}

// ---------------- attention: one block per (b, head) ----------------
// Q,K: [bh][208][64] bf16 (Q pre-scaled 1/8). Vt: [bh][64][208]. O: [6304][768] bf16 (col h*64+d).
__global__ __launch_bounds__(256) void attn_k(
    const bf16* __restrict__ Q, const bf16* __restrict__ Kb,
    const bf16* __restrict__ Vt, bf16* __restrict__ O)
{
  __shared__ alignas(16) bf16 Ks[208 * 72];       // [m][64] pad 72
  __shared__ alignas(16) bf16 Vs[64 * 232];       // [d][208] pad 232 (cols 197..231 zeroed)
  __shared__ alignas(16) bf16 Ps[4][16 * 232];    // per-wave P tile [16][208] pad 232
  const int bh = blockIdx.x;
  const int b = bh / 12, hh = bh - b * 12;
  const bf16* Qg = Q + (size_t)bh * 208 * 64;
  const bf16* Kg = Kb + (size_t)bh * 208 * 64;
  const bf16* Vg = Vt + (size_t)bh * 64 * 208;
  const int tid = threadIdx.x, lane = tid & 63, wave = tid >> 6;
  const int lrow = lane & 15, lgrp = lane >> 4;

  for (int q = tid; q < 1664; q += 256) {         // K: 208 rows x 8 chunks
    int r = q >> 3, c = (q & 7) << 3;
    *(uint4*)(Ks + r * 72 + c) = *(const uint4*)(Kg + r * 64 + c);
  }
  for (int q = tid; q < 1664; q += 256) {         // Vt: 64 rows x 26 chunks
    int r = q / 26, c = (q - r * 26) << 3;
    *(uint4*)(Vs + r * 232 + c) = *(const uint4*)(Vg + r * 208 + c);
  }
  __syncthreads();
  // zero Vt pad cols 197..231 (uninitialized global pad could be NaN; 0*NaN would poison PV)
  for (int q = tid; q < 64 * 35; q += 256) {
    int r = q / 35, c = 197 + (q - r * 35);
    Vs[r * 232 + c] = (bf16)0.0f;
  }
  __syncthreads();

  for (int ti = 0; ti < 4; ++ti) {
    const int rt = wave * 4 + ti;                 // 13 valid query row-tiles of 16
    if (rt >= 13) break;
    bf16x8 a0 = *(const bf16x8*)(Qg + (rt * 16 + lrow) * 64 + (lgrp << 3));
    bf16x8 a1 = *(const bf16x8*)(Qg + (rt * 16 + lrow) * 64 + 32 + (lgrp << 3));
    f32x4 sacc[13];
    #pragma unroll
    for (int ct = 0; ct < 13; ++ct) {
      bf16x8 b0 = *(const bf16x8*)(Ks + (ct * 16 + lrow) * 72 + (lgrp << 3));
      bf16x8 b1 = *(const bf16x8*)(Ks + (ct * 16 + lrow) * 72 + 32 + (lgrp << 3));
      f32x4 s = {};
      s = mfma_bf16(a0, b0, s);
      s = mfma_bf16(a1, b1, s);
      sacc[ct] = s;
    }
    bf16* Pw = Ps[wave];
    float inv4[4];
    #pragma unroll
    for (int j = 0; j < 4; ++j) {
      const int prow = (lgrp << 2) + j;
      float mx = -3.0e38f;
      #pragma unroll
      for (int ct = 0; ct < 13; ++ct) {
        int c = ct * 16 + lrow;
        if (c < 197) mx = fmaxf(mx, sacc[ct][j]);
      }
      #pragma unroll
      for (int o = 1; o < 16; o <<= 1) mx = fmaxf(mx, __shfl_xor(mx, o));
      float sum = 0.0f;
      #pragma unroll
      for (int ct = 0; ct < 13; ++ct) {
        int c = ct * 16 + lrow;
        float p = (c < 197) ? expf(sacc[ct][j] - mx) : 0.0f;
        sum += p;
        Pw[prow * 232 + c] = (bf16)p;
      }
      #pragma unroll
      for (int o = 1; o < 16; o <<= 1) sum += __shfl_xor(sum, o);
      inv4[j] = 1.0f / sum;
      Pw[prow * 232 + 208 + lrow] = (bf16)0.0f;   // zero P cols 208..223 (read by mc loop)
    }
    f32x4 oacc[4] = {};
    #pragma unroll
    for (int mc = 0; mc < 7; ++mc) {              // K-dim 224
      bf16x8 pa = *(const bf16x8*)(Pw + lrow * 232 + mc * 32 + (lgrp << 3));
      #pragma unroll
      for (int n2 = 0; n2 < 4; ++n2) {
        bf16x8 vb = *(const bf16x8*)(Vs + (n2 * 16 + lrow) * 232 + mc * 32 + (lgrp << 3));
        oacc[n2] = mfma_bf16(pa, vb, oacc[n2]);
      }
    }
    #pragma unroll
    for (int n2 = 0; n2 < 4; ++n2) {
      const int d = n2 * 16 + lrow;
      #pragma unroll
      for (int j = 0; j < 4; ++j) {
        const int qrow = rt * 16 + (lgrp << 2) + j;
        if (qrow < 197)
          O[((size_t)b * 197 + qrow) * 768 + hh * 64 + d] = (bf16)(oacc[n2][j] * inv4[j]);
      }
    }
  }
}

// ---------------- final head ----------------

__global__ __launch_bounds__(256) void head1_k(const float* __restrict__ rep, const float* __restrict__ wh,
                                               const float* __restrict__ bh, float* __restrict__ hid) {
  __shared__ float r[768];
  int b = blockIdx.x;
  for (int i = threadIdx.x; i < 768; i += 256) r[i] = rep[b * 768 + i];
  __syncthreads();
  for (int j = threadIdx.x; j < 768; j += 256) {
    const float* w = wh + (size_t)j * 768;
    float acc = 0.f;
    for (int i = 0; i < 768; ++i) acc += r[i] * w[i];
    hid[b * 768 + j] = tanhf(acc + bh[j]);
  }
}

__global__ __launch_bounds__(256) void head2_k(const float* __restrict__ hid, const float* __restrict__ wc,
                                               const float* __restrict__ bc, float* __restrict__ out) {
  __shared__ float r[768];
  int b = blockIdx.x;
  for (int i = threadIdx.x; i < 768; i += 256) r[i] = hid[b * 768 + i];
  __syncthreads();
  for (int j = threadIdx.x; j < 1000; j += 256) {
    const float* w = wc + (size_t)j * 768;
    float acc = 0.f;
    for (int i = 0; i < 768; ++i) acc += r[i] * w[i];
    out[b * 1000 + j] = acc + bc[j];
  }
}

// ---------------- driver ----------------

extern "C" void kernel_launch(void* const* d_in, const int* in_sizes, int n_in,
                              void* d_out, int out_size, void* d_ws, size_t ws_size,
                              hipStream_t stream) {
  const float* x      = (const float*)d_in[0];
  const float* w_proj = (const float*)d_in[1];
  const float* b_proj = (const float*)d_in[2];
  const float* cls    = (const float*)d_in[3];
  const float* ln1g   = (const float*)d_in[4];
  const float* ln1b   = (const float*)d_in[5];
  const float* w_qkv  = (const float*)d_in[6];
  const float* b_qkv  = (const float*)d_in[7];
  const float* w_o    = (const float*)d_in[8];
  const float* b_o    = (const float*)d_in[9];
  const float* ln2g   = (const float*)d_in[10];
  const float* ln2b   = (const float*)d_in[11];
  const float* w_fc1  = (const float*)d_in[12];
  const float* b_fc1  = (const float*)d_in[13];
  const float* w_fc2  = (const float*)d_in[14];
  const float* b_fc2  = (const float*)d_in[15];
  const float* lnfg   = (const float*)d_in[16];
  const float* lnfb   = (const float*)d_in[17];
  const float* w_h    = (const float*)d_in[18];
  const float* b_h    = (const float*)d_in[19];
  const float* w_c    = (const float*)d_in[20];
  const float* b_c    = (const float*)d_in[21];
  float* out = (float*)d_out;

  uint8_t* ws = (uint8_t*)d_ws;
  size_t off = 0;
  auto alloc = [&](size_t bytes) -> void* {
    void* p = ws + off; off += (bytes + 255) & ~(size_t)255; return p;
  };
  float* h    = (float*)alloc(6400ull * 768 * 4);   // residual stream fp32 (padded to 6400 rows)
  bf16*  ybf  = (bf16*) alloc(6400ull * 768 * 2);   // LN output bf16
  bf16*  qb   = (bf16*) alloc(32ull * 12 * 208 * 64 * 2);
  bf16*  kbuf = (bf16*) alloc(32ull * 12 * 208 * 64 * 2);
  bf16*  vtb  = (bf16*) alloc(32ull * 12 * 64 * 208 * 2);
  bf16*  ob   = (bf16*) alloc(6400ull * 768 * 2);
  bf16*  f1   = (bf16*) alloc(6400ull * 3072 * 2);
  float* pos  = (float*)alloc(197ull * 768 * 4);
  bf16* wprojB = (bf16*)alloc(768ull * 768 * 2);
  bf16* wqkvB  = (bf16*)alloc(2304ull * 768 * 2);
  bf16* woB    = (bf16*)alloc(768ull * 768 * 2);
  bf16* wfc1B  = (bf16*)alloc(3072ull * 768 * 2);
  bf16* wfc2B  = (bf16*)alloc(768ull * 3072 * 2);
  float* rep   = (float*)alloc(32ull * 768 * 4);
  float* hid   = (float*)alloc(32ull * 768 * 4);
  bf16* patches = f1;   // alias: patches dead before FC1 first writes f1

  f2b_k<<<(768 * 768 + 255) / 256, 256, 0, stream>>>(w_proj, wprojB, 768 * 768);
  f2b_k<<<(2304 * 768 + 255) / 256, 256, 0, stream>>>(w_qkv, wqkvB, 2304 * 768);
  f2b_k<<<(768 * 768 + 255) / 256, 256, 0, stream>>>(w_o, woB, 768 * 768);
  f2b_k<<<(3072 * 768 + 255) / 256, 256, 0, stream>>>(w_fc1, wfc1B, 3072 * 768);
  f2b_k<<<(768 * 3072 + 255) / 256, 256, 0, stream>>>(w_fc2, wfc2B, 768 * 3072);
  posenc_k<<<197, 256, 0, stream>>>(pos);
  patchify_k<<<6272 * 768 / 256, 256, 0, stream>>>(x, patches);
  gemm_nt<0><<<dim3(49, 6), 256, 0, stream>>>(patches, wprojB, 6272, 768, 768, b_proj,
                                              h, nullptr, nullptr, nullptr, nullptr);
  combine_k<<<6304 * 768 / 256, 256, 0, stream>>>(h, pos, cls);

  for (int layer = 0; layer < 12; ++layer) {
    ln_k<1><<<6304, 256, 0, stream>>>(h, ln1g, ln1b, ybf, 768);
    gemm_nt<1><<<dim3(50, 18), 256, 0, stream>>>(ybf, wqkvB, 6304, 2304, 768, b_qkv,
                                                 nullptr, nullptr, qb, kbuf, vtb);
    attn_k<<<384, 256, 0, stream>>>(qb, kbuf, vtb, ob);
    gemm_nt<2><<<dim3(50, 6), 256, 0, stream>>>(ob, woB, 6304, 768, 768, b_o,
                                                h, nullptr, nullptr, nullptr, nullptr);
    ln_k<1><<<6304, 256, 0, stream>>>(h, ln2g, ln2b, ybf, 768);
    gemm_nt<3><<<dim3(50, 24), 256, 0, stream>>>(ybf, wfc1B, 6304, 3072, 768, b_fc1,
                                                 nullptr, f1, nullptr, nullptr, nullptr);
    gemm_nt<2><<<dim3(50, 6), 256, 0, stream>>>(f1, wfc2B, 6304, 768, 3072, b_fc2,
                                                h, nullptr, nullptr, nullptr, nullptr);
  }

  ln_k<0><<<32, 256, 0, stream>>>(h, lnfg, lnfb, rep, 197 * 768);
  head1_k<<<32, 256, 0, stream>>>(rep, w_h, b_h, hid);
  head2_k<<<32, 256, 0, stream>>>(hid, w_c, b_c, out);
}

// Round 2
// 3753.297 us; speedup vs baseline: 2.2409x; 2.2409x over previous
//
#include <hip/hip_runtime.h>
#include <hip/hip_bf16.h>

// ViT forward, MI355X gfx950. Round 2: m97-style GEMM (global_load_lds + XOR swizzle),
// transposed QKV output (contiguous epilogue, coalesced attention gather).

typedef __bf16 bf16;
typedef __bf16 bf16x8 __attribute__((ext_vector_type(8)));
typedef float  f32x4  __attribute__((ext_vector_type(4)));

typedef __attribute__((address_space(1))) const unsigned int gu32;
typedef __attribute__((address_space(3))) unsigned int lu32;

static __device__ __forceinline__ f32x4 mfma_bf16(bf16x8 a, bf16x8 b, f32x4 c) {
  return __builtin_amdgcn_mfma_f32_16x16x32_bf16(a, b, c, 0, 0, 0);
}
static __device__ __forceinline__ void gll16(const bf16* g, bf16* l) {
  __builtin_amdgcn_global_load_lds((gu32*)g, (lu32*)l, 16, 0, 0);
}

// ---------------- small setup kernels ----------------

__global__ __launch_bounds__(256) void f2b_k(const float* __restrict__ a, bf16* __restrict__ o, int n) {
  int i = blockIdx.x * 256 + threadIdx.x;
  if (i < n) o[i] = (bf16)a[i];
}

__global__ __launch_bounds__(256) void posenc_k(float* __restrict__ pos) {
  int l = blockIdx.x;
  for (int d = threadIdx.x; d < 768; d += 256) {
    int ieff = d & ~1;
    float ang = (float)l * expf(-(float)ieff * (9.210340371976184f / 768.0f)); // 10000^{-i/768}
    pos[l * 768 + d] = (d & 1) ? cosf(ang) : sinf(ang);
  }
}

// patches[t, c*256+i*16+j] = x[b, c, ph*16+i, pw*16+j],  t = b*196 + ph*14 + pw
__global__ __launch_bounds__(256) void patchify_k(const float* __restrict__ x, bf16* __restrict__ p) {
  int idx = blockIdx.x * 256 + threadIdx.x;     // 6272*768 exact
  int t = idx / 768, col = idx - t * 768;
  int b = t / 196, pp = t - b * 196;
  int ph = pp / 14, pw = pp - ph * 14;
  int c = col >> 8, r = col & 255, i = r >> 4, j = r & 15;
  p[idx] = (bf16)x[((b * 3 + c) * 224 + ph * 16 + i) * 224 + pw * 16 + j];
}

__global__ __launch_bounds__(256) void combine_k(float* __restrict__ h, const float* __restrict__ pos,
                                                 const float* __restrict__ cls) {
  int idx = blockIdx.x * 256 + threadIdx.x;     // 6304*768 exact
  int t = idx / 768, d = idx - t * 768;
  int l = t % 197;
  float p = pos[l * 768 + d];
  if (l == 0) h[idx] = cls[d] + p;
  else        h[idx] += p;
}

// LayerNorm over 768. OBF=1: bf16 out. OBF=0: fp32 out.
template<int OBF>
__global__ __launch_bounds__(256) void ln_k(const float* __restrict__ x, const float* __restrict__ g,
                                            const float* __restrict__ bb, void* __restrict__ yv,
                                            int instride) {
  int row = blockIdx.x;
  const float* xr = x + (size_t)row * instride;
  int tid = threadIdx.x;
  float v0 = xr[tid], v1 = xr[tid + 256], v2 = xr[tid + 512];
  float s = v0 + v1 + v2, s2 = v0 * v0 + v1 * v1 + v2 * v2;
  #pragma unroll
  for (int o = 1; o < 64; o <<= 1) { s += __shfl_xor(s, o); s2 += __shfl_xor(s2, o); }
  __shared__ float red[8];
  if ((tid & 63) == 0) { red[tid >> 6] = s; red[4 + (tid >> 6)] = s2; }
  __syncthreads();
  float S = red[0] + red[1] + red[2] + red[3];
  float S2 = red[4] + red[5] + red[6] + red[7];
  float m = S * (1.0f / 768.0f);
  float inv = rsqrtf(S2 * (1.0f / 768.0f) - m * m + 1e-5f);
  if constexpr (OBF) {
    bf16* yr = (bf16*)yv + (size_t)row * 768;
    yr[tid]       = (bf16)((v0 - m) * inv * g[tid]       + bb[tid]);
    yr[tid + 256] = (bf16)((v1 - m) * inv * g[tid + 256] + bb[tid + 256]);
    yr[tid + 512] = (bf16)((v2 - m) * inv * g[tid + 512] + bb[tid + 512]);
  } else {
    float* yr = (float*)yv + (size_t)row * 768;
    yr[tid]       = (v0 - m) * inv * g[tid]       + bb[tid];
    yr[tid + 256] = (v1 - m) * inv * g[tid + 256] + bb[tid + 256];
    yr[tid + 512] = (v2 - m) * inv * g[tid + 512] + bb[tid + 512];
  }
}

// ---------------- NT GEMM, m97 structure ----------------
// C[M,N] = A[M,K] * B[N,K]^T. 128xBN tile, BK=64, 4 waves.
// LDS linear [rows][64]; global_load_lds w=16 with XOR chunk-swizzle on source,
// same XOR on ds_read address (involution both sides, linear dest).
// EPI: 0=PROJ (h row remap, fp32)  1=QKVT (bf16, bias by ROW, rows<768 *0.125, stride ldc)
//      2=ACCUM (outF[t*768+col]+=)  3=FC1 gelu (bf16, stride 3072)
template<int BN, int EPI>
__global__ __launch_bounds__(256) void gemm2(
    const bf16* __restrict__ A, const bf16* __restrict__ B,
    int M, int N, int K, int ldc, const float* __restrict__ bias,
    float* __restrict__ outF, bf16* __restrict__ outB)
{
  constexpr int WN = (BN == 128) ? 64 : 32;   // per-wave N extent
  constexpr int NI = WN / 16;
  constexpr int NB = BN / 32;                 // Bs stage insts per wave
  __shared__ alignas(16) bf16 As[128 * 64];
  __shared__ alignas(16) bf16 Bs[BN * 64];
  const int tid = threadIdx.x;
  const int lane = tid & 63, wave = tid >> 6;
  const int wr = wave >> 1, wc = wave & 1;
  const int lrow = lane & 15, lgrp = lane >> 4;
  const int row0 = blockIdx.x * 128, col0 = blockIdx.y * BN;

  f32x4 acc[4][NI] = {};
  const bf16* Agb = A + (size_t)row0 * K;
  const bf16* Bgb = B + (size_t)col0 * K;
  const int srow = lane >> 3;                 // lane's row within 8-row stripe
  const int schunk = lane & 7;

  const int nk = K >> 6;
  for (int kt = 0; kt < nk; ++kt) {
    // stage: each wave DMAs 1KB stripes (8 rows x 64 bf16), source chunk XOR-swizzled
    const bf16* Ag = Agb + kt * 64;
    const bf16* Bg = Bgb + kt * 64;
    #pragma unroll
    for (int i = 0; i < 4; ++i) {
      int rr = (wave * 4 + i) * 8 + srow;
      int g = schunk ^ (rr & 7);
      gll16(Ag + (size_t)rr * K + g * 8, As + (wave * 4 + i) * 512);
    }
    #pragma unroll
    for (int i = 0; i < NB; ++i) {
      int rr = (wave * NB + i) * 8 + srow;
      int g = schunk ^ (rr & 7);
      gll16(Bg + (size_t)rr * K + g * 8, Bs + (wave * NB + i) * 512);
    }
    __syncthreads();   // drains vmcnt(0) + barrier
    #pragma unroll
    for (int kk = 0; kk < 2; ++kk) {
      bf16x8 af[4], bfr[NI];
      #pragma unroll
      for (int mi = 0; mi < 4; ++mi) {
        int r = wr * 64 + mi * 16 + lrow;
        af[mi] = *(const bf16x8*)(As + r * 64 + (((kk * 4 + lgrp) ^ (r & 7)) << 3));
      }
      #pragma unroll
      for (int ni = 0; ni < NI; ++ni) {
        int r = wc * WN + ni * 16 + lrow;
        bfr[ni] = *(const bf16x8*)(Bs + r * 64 + (((kk * 4 + lgrp) ^ (r & 7)) << 3));
      }
      #pragma unroll
      for (int mi = 0; mi < 4; ++mi)
        #pragma unroll
        for (int ni = 0; ni < NI; ++ni)
          acc[mi][ni] = mfma_bf16(af[mi], bfr[ni], acc[mi][ni]);
    }
    __syncthreads();
  }

  // epilogue: C frag layout col = lane&15, row = (lane>>4)*4 + j
  #pragma unroll
  for (int ni = 0; ni < NI; ++ni) {
    const int col = col0 + wc * WN + ni * 16 + lrow;
    float bs = 0.0f;
    if (EPI != 1) bs = bias[col];
    #pragma unroll
    for (int mi = 0; mi < 4; ++mi) {
      const int rbase = row0 + wr * 64 + mi * 16 + (lgrp << 2);
      #pragma unroll
      for (int j = 0; j < 4; ++j) {
        const int t = rbase + j;
        if (EPI == 1) {
          float val = acc[mi][ni][j] + bias[t];
          if (t < 768) val *= 0.125f;
          outB[(size_t)t * ldc + col] = (bf16)val;
        } else {
          if (t >= M) continue;
          float val = acc[mi][ni][j] + bs;
          if (EPI == 0) {
            int b = t / 196, p = t - b * 196;
            outF[((size_t)(b * 197 + 1 + p)) * 768 + col] = val;
          } else if (EPI == 2) {
            outF[(size_t)t * 768 + col] += val;
          } else {
            outB[(size_t)t * 3072 + col] = (bf16)(0.5f * val * (1.0f + erff(val * 0.70710678118654752f)));
          }
        }
      }
    }
  }
}

// ---------------- attention: one block per (b, head) ----------------
// Ct: QKV^T [2304][6400] bf16 (rows n = comp*768 + d*12 + h; Q rows pre-scaled 1/8).
// O: [6304][768] bf16.
__global__ __launch_bounds__(256) void attn_k(const bf16* __restrict__ Ct, bf16* __restrict__ O) {
  __shared__ alignas(16) bf16 Ks[208 * 72];       // [l][d] pad 72
  __shared__ alignas(16) bf16 Vs[64 * 232];       // [d][l] pad 232, cols 197..223 zeroed
  __shared__ alignas(16) bf16 Ps[4][16 * 232];    // per-wave P tile
  const int bh = blockIdx.x;
  const int b = bh / 12, hh = bh - b * 12;
  const int tid = threadIdx.x, lane = tid & 63, wave = tid >> 6;
  const int lrow = lane & 15, lgrp = lane >> 4;
  const int tcol0 = b * 197;

  // stage K: coalesced over l (contiguous in Ct row direction)
  for (int idx = tid; idx < 64 * 208; idx += 256) {
    int d = idx / 208, l = idx - d * 208;
    if (l < 197)
      Ks[l * 72 + d] = Ct[((size_t)(768 + d * 12 + hh)) * 6400 + tcol0 + l];
  }
  // stage V^T: [d][l], zero-pad l in [197,224)
  for (int idx = tid; idx < 64 * 224; idx += 256) {
    int d = idx / 224, l = idx - d * 224;
    bf16 v = (bf16)0.0f;
    if (l < 197) v = Ct[((size_t)(1536 + d * 12 + hh)) * 6400 + tcol0 + l];
    Vs[d * 232 + l] = v;
  }
  __syncthreads();

  for (int ti = 0; ti < 4; ++ti) {
    const int rt = wave * 4 + ti;                 // 13 valid q row-tiles
    if (rt >= 13) break;
    // Q frags: gather from Ct (rows d*12+h, col tcol0 + qrow), stride-12 rows
    const bf16* qp = Ct + (size_t)hh * 6400 + tcol0 + rt * 16 + lrow;
    bf16x8 a0, a1;
    #pragma unroll
    for (int e = 0; e < 8; ++e) {
      a0[e] = qp[(size_t)(lgrp * 8 + e) * 76800];        // d*12*6400
      a1[e] = qp[(size_t)(lgrp * 8 + e + 32) * 76800];
    }
    f32x4 sacc[13];
    #pragma unroll
    for (int ct = 0; ct < 13; ++ct) {
      bf16x8 b0 = *(const bf16x8*)(Ks + (ct * 16 + lrow) * 72 + (lgrp << 3));
      bf16x8 b1 = *(const bf16x8*)(Ks + (ct * 16 + lrow) * 72 + 32 + (lgrp << 3));
      f32x4 s = {};
      s = mfma_bf16(a0, b0, s);
      s = mfma_bf16(a1, b1, s);
      sacc[ct] = s;
    }
    bf16* Pw = Ps[wave];
    float inv4[4];
    #pragma unroll
    for (int j = 0; j < 4; ++j) {
      const int prow = (lgrp << 2) + j;
      float mx = -3.0e38f;
      #pragma unroll
      for (int ct = 0; ct < 13; ++ct) {
        int c = ct * 16 + lrow;
        if (c < 197) mx = fmaxf(mx, sacc[ct][j]);
      }
      #pragma unroll
      for (int o = 1; o < 16; o <<= 1) mx = fmaxf(mx, __shfl_xor(mx, o));
      float sum = 0.0f;
      #pragma unroll
      for (int ct = 0; ct < 13; ++ct) {
        int c = ct * 16 + lrow;
        float p = (c < 197) ? expf(sacc[ct][j] - mx) : 0.0f;
        sum += p;
        Pw[prow * 232 + c] = (bf16)p;
      }
      #pragma unroll
      for (int o = 1; o < 16; o <<= 1) sum += __shfl_xor(sum, o);
      inv4[j] = 1.0f / sum;
      Pw[prow * 232 + 208 + lrow] = (bf16)0.0f;   // zero P cols 208..223
    }
    f32x4 oacc[4] = {};
    #pragma unroll
    for (int mc = 0; mc < 7; ++mc) {              // K-dim 224
      bf16x8 pa = *(const bf16x8*)(Pw + lrow * 232 + mc * 32 + (lgrp << 3));
      #pragma unroll
      for (int n2 = 0; n2 < 4; ++n2) {
        bf16x8 vb = *(const bf16x8*)(Vs + (n2 * 16 + lrow) * 232 + mc * 32 + (lgrp << 3));
        oacc[n2] = mfma_bf16(pa, vb, oacc[n2]);
      }
    }
    #pragma unroll
    for (int n2 = 0; n2 < 4; ++n2) {
      const int d = n2 * 16 + lrow;
      #pragma unroll
      for (int j = 0; j < 4; ++j) {
        const int qrow = rt * 16 + (lgrp << 2) + j;
        if (qrow < 197)
          O[((size_t)tcol0 + qrow) * 768 + hh * 64 + d] = (bf16)(oacc[n2][j] * inv4[j]);
      }
    }
  }
}

// ---------------- final head ----------------

__global__ __launch_bounds__(256) void head1_k(const float* __restrict__ rep, const float* __restrict__ wh,
                                               const float* __restrict__ bh, float* __restrict__ hid) {
  __shared__ float r[768];
  int b = blockIdx.x;
  for (int i = threadIdx.x; i < 768; i += 256) r[i] = rep[b * 768 + i];
  __syncthreads();
  for (int j = threadIdx.x; j < 768; j += 256) {
    const float* w = wh + (size_t)j * 768;
    float acc = 0.f;
    for (int i = 0; i < 768; ++i) acc += r[i] * w[i];
    hid[b * 768 + j] = tanhf(acc + bh[j]);
  }
}

__global__ __launch_bounds__(256) void head2_k(const float* __restrict__ hid, const float* __restrict__ wc,
                                               const float* __restrict__ bc, float* __restrict__ out) {
  __shared__ float r[768];
  int b = blockIdx.x;
  for (int i = threadIdx.x; i < 768; i += 256) r[i] = hid[b * 768 + i];
  __syncthreads();
  for (int j = threadIdx.x; j < 1000; j += 256) {
    const float* w = wc + (size_t)j * 768;
    float acc = 0.f;
    for (int i = 0; i < 768; ++i) acc += r[i] * w[i];
    out[b * 1000 + j] = acc + bc[j];
  }
}

// ---------------- driver ----------------

extern "C" void kernel_launch(void* const* d_in, const int* in_sizes, int n_in,
                              void* d_out, int out_size, void* d_ws, size_t ws_size,
                              hipStream_t stream) {
  const float* x      = (const float*)d_in[0];
  const float* w_proj = (const float*)d_in[1];
  const float* b_proj = (const float*)d_in[2];
  const float* cls    = (const float*)d_in[3];
  const float* ln1g   = (const float*)d_in[4];
  const float* ln1b   = (const float*)d_in[5];
  const float* w_qkv  = (const float*)d_in[6];
  const float* b_qkv  = (const float*)d_in[7];
  const float* w_o    = (const float*)d_in[8];
  const float* b_o    = (const float*)d_in[9];
  const float* ln2g   = (const float*)d_in[10];
  const float* ln2b   = (const float*)d_in[11];
  const float* w_fc1  = (const float*)d_in[12];
  const float* b_fc1  = (const float*)d_in[13];
  const float* w_fc2  = (const float*)d_in[14];
  const float* b_fc2  = (const float*)d_in[15];
  const float* lnfg   = (const float*)d_in[16];
  const float* lnfb   = (const float*)d_in[17];
  const float* w_h    = (const float*)d_in[18];
  const float* b_h    = (const float*)d_in[19];
  const float* w_c    = (const float*)d_in[20];
  const float* b_c    = (const float*)d_in[21];
  float* out = (float*)d_out;

  uint8_t* ws = (uint8_t*)d_ws;
  size_t off = 0;
  auto alloc = [&](size_t bytes) -> void* {
    void* p = ws + off; off += (bytes + 255) & ~(size_t)255; return p;
  };
  float* h    = (float*)alloc(6400ull * 768 * 4);   // residual fp32
  bf16*  ybf  = (bf16*) alloc(6400ull * 768 * 2);   // LN out bf16 (pad rows = poison, finite)
  bf16*  ct   = (bf16*) alloc(2304ull * 6400 * 2);  // QKV^T
  bf16*  ob   = (bf16*) alloc(6400ull * 768 * 2);   // attention out bf16
  bf16*  f1   = (bf16*) alloc(6400ull * 3072 * 2);  // FC1 out bf16
  float* pos  = (float*)alloc(197ull * 768 * 4);
  bf16* wprojB = (bf16*)alloc(768ull * 768 * 2);
  bf16* wqkvB  = (bf16*)alloc(2304ull * 768 * 2);
  bf16* woB    = (bf16*)alloc(768ull * 768 * 2);
  bf16* wfc1B  = (bf16*)alloc(3072ull * 768 * 2);
  bf16* wfc2B  = (bf16*)alloc(768ull * 3072 * 2);
  float* rep   = (float*)alloc(32ull * 768 * 4);
  float* hid   = (float*)alloc(32ull * 768 * 4);
  bf16* patches = f1;   // alias: patches dead before FC1 first writes f1

  f2b_k<<<(768 * 768 + 255) / 256, 256, 0, stream>>>(w_proj, wprojB, 768 * 768);
  f2b_k<<<(2304 * 768 + 255) / 256, 256, 0, stream>>>(w_qkv, wqkvB, 2304 * 768);
  f2b_k<<<(768 * 768 + 255) / 256, 256, 0, stream>>>(w_o, woB, 768 * 768);
  f2b_k<<<(3072 * 768 + 255) / 256, 256, 0, stream>>>(w_fc1, wfc1B, 3072 * 768);
  f2b_k<<<(768 * 3072 + 255) / 256, 256, 0, stream>>>(w_fc2, wfc2B, 768 * 3072);
  posenc_k<<<197, 256, 0, stream>>>(pos);
  patchify_k<<<6272 * 768 / 256, 256, 0, stream>>>(x, patches);
  gemm2<64, 0><<<dim3(49, 12), 256, 0, stream>>>(patches, wprojB, 6272, 768, 768, 768, b_proj, h, nullptr);
  combine_k<<<6304 * 768 / 256, 256, 0, stream>>>(h, pos, cls);

  for (int layer = 0; layer < 12; ++layer) {
    ln_k<1><<<6304, 256, 0, stream>>>(h, ln1g, ln1b, ybf, 768);
    // QKV^T: A = w_qkv [2304][768], B = ybf [6400][768] -> Ct [2304][6400]
    gemm2<128, 1><<<dim3(18, 50), 256, 0, stream>>>(wqkvB, ybf, 2304, 6400, 768, 6400, b_qkv, nullptr, ct);
    attn_k<<<384, 256, 0, stream>>>(ct, ob);
    gemm2<64, 2><<<dim3(50, 12), 256, 0, stream>>>(ob, woB, 6304, 768, 768, 768, b_o, h, nullptr);
    ln_k<1><<<6304, 256, 0, stream>>>(h, ln2g, ln2b, ybf, 768);
    gemm2<128, 3><<<dim3(50, 24), 256, 0, stream>>>(ybf, wfc1B, 6304, 3072, 768, 3072, b_fc1, nullptr, f1);
    gemm2<64, 2><<<dim3(50, 12), 256, 0, stream>>>(f1, wfc2B, 6304, 768, 3072, 768, b_fc2, h, nullptr);
  }

  ln_k<0><<<32, 256, 0, stream>>>(h, lnfg, lnfb, rep, 197 * 768);
  head1_k<<<32, 256, 0, stream>>>(rep, w_h, b_h, hid);
  head2_k<<<32, 256, 0, stream>>>(hid, w_c, b_c, out);
}

// Round 3
// 2756.400 us; speedup vs baseline: 3.0513x; 1.3617x over previous
//
#include <hip/hip_runtime.h>
#include <hip/hip_bf16.h>

// ViT forward, MI355X gfx950. Round 3: 8-wave attention w/ LDS-staged Q + swizzle,
// MFMA head GEMMs, wave-per-row LayerNorm. Ct token columns padded to b*200+l.

typedef __bf16 bf16;
typedef __bf16 bf16x8 __attribute__((ext_vector_type(8)));
typedef __bf16 bf16x4 __attribute__((ext_vector_type(4)));
typedef float  f32x4  __attribute__((ext_vector_type(4)));

typedef __attribute__((address_space(1))) const unsigned int gu32;
typedef __attribute__((address_space(3))) unsigned int lu32;

static __device__ __forceinline__ f32x4 mfma_bf16(bf16x8 a, bf16x8 b, f32x4 c) {
  return __builtin_amdgcn_mfma_f32_16x16x32_bf16(a, b, c, 0, 0, 0);
}
static __device__ __forceinline__ void gll16(const bf16* g, bf16* l) {
  __builtin_amdgcn_global_load_lds((gu32*)g, (lu32*)l, 16, 0, 0);
}

// ---------------- small setup kernels ----------------

__global__ __launch_bounds__(256) void f2b_k(const float* __restrict__ a, bf16* __restrict__ o, int n) {
  int i = blockIdx.x * 256 + threadIdx.x;
  if (i < n) o[i] = (bf16)a[i];
}

__global__ __launch_bounds__(256) void posenc_k(float* __restrict__ pos) {
  int l = blockIdx.x;
  for (int d = threadIdx.x; d < 768; d += 256) {
    int ieff = d & ~1;
    float ang = (float)l * expf(-(float)ieff * (9.210340371976184f / 768.0f)); // 10000^{-i/768}
    pos[l * 768 + d] = (d & 1) ? cosf(ang) : sinf(ang);
  }
}

// patches[t, c*256+i*16+j] = x[b, c, ph*16+i, pw*16+j],  t = b*196 + ph*14 + pw
__global__ __launch_bounds__(256) void patchify_k(const float* __restrict__ x, bf16* __restrict__ p) {
  int idx = blockIdx.x * 256 + threadIdx.x;     // 6272*768 exact
  int t = idx / 768, col = idx - t * 768;
  int b = t / 196, pp = t - b * 196;
  int ph = pp / 14, pw = pp - ph * 14;
  int c = col >> 8, r = col & 255, i = r >> 4, j = r & 15;
  p[idx] = (bf16)x[((b * 3 + c) * 224 + ph * 16 + i) * 224 + pw * 16 + j];
}

__global__ __launch_bounds__(256) void combine_k(float* __restrict__ h, const float* __restrict__ pos,
                                                 const float* __restrict__ cls) {
  int idx = blockIdx.x * 256 + threadIdx.x;     // 6304*768 exact
  int t = idx / 768, d = idx - t * 768;
  int l = t % 197;
  float p = pos[l * 768 + d];
  if (l == 0) h[idx] = cls[d] + p;
  else        h[idx] += p;
}

// LayerNorm over 768, one wave per row, 4 rows/block, bf16 out.
// PAD=1: output row index remapped t=b*197+l -> b*200+l (for QKV-GEMM B operand).
template<int PAD>
__global__ __launch_bounds__(256) void ln4_k(const float* __restrict__ x, const float* __restrict__ g,
                                             const float* __restrict__ bb, bf16* __restrict__ y,
                                             int nrows, int instride) {
  const int wave = threadIdx.x >> 6, lane = threadIdx.x & 63;
  const int row = blockIdx.x * 4 + wave;
  if (row >= nrows) return;
  const float4* x4 = (const float4*)(x + (size_t)row * instride);
  float4 v0 = x4[lane], v1 = x4[lane + 64], v2 = x4[lane + 128];
  float s  = v0.x + v0.y + v0.z + v0.w + v1.x + v1.y + v1.z + v1.w + v2.x + v2.y + v2.z + v2.w;
  float s2 = v0.x*v0.x + v0.y*v0.y + v0.z*v0.z + v0.w*v0.w
           + v1.x*v1.x + v1.y*v1.y + v1.z*v1.z + v1.w*v1.w
           + v2.x*v2.x + v2.y*v2.y + v2.z*v2.z + v2.w*v2.w;
  #pragma unroll
  for (int o = 1; o < 64; o <<= 1) { s += __shfl_xor(s, o); s2 += __shfl_xor(s2, o); }
  float m = s * (1.0f / 768.0f);
  float inv = rsqrtf(s2 * (1.0f / 768.0f) - m * m + 1e-5f);
  int orow = row;
  if (PAD) { int bq = row / 197; orow = row + bq * 3; }
  bf16* yr = y + (size_t)orow * 768;
  const float4* g4 = (const float4*)g;
  const float4* b4 = (const float4*)bb;
  #pragma unroll
  for (int i = 0; i < 3; ++i) {
    int idx = lane + i * 64;
    float4 vv = (i == 0) ? v0 : (i == 1) ? v1 : v2;
    float4 gv = g4[idx], bv = b4[idx];
    bf16x4 o;
    o[0] = (bf16)((vv.x - m) * inv * gv.x + bv.x);
    o[1] = (bf16)((vv.y - m) * inv * gv.y + bv.y);
    o[2] = (bf16)((vv.z - m) * inv * gv.z + bv.z);
    o[3] = (bf16)((vv.w - m) * inv * gv.w + bv.w);
    *(bf16x4*)(yr + idx * 4) = o;
  }
}

// ---------------- NT GEMM, m97 structure ----------------
// C[M,N] = A[M,K] * B[N,K]^T. 128xBN tile, BK=64, 4 waves.
// EPI: 0=PROJ (h row remap, fp32)  1=QKVT (bf16, bias by ROW, rows<768 *0.125, stride ldc)
//      2=ACCUM (outF[t*768+col]+=)  3=FC1 gelu (bf16, stride 3072)
//      4=TANH (bf16, stride 768)    5=GUARDED fp32 store (stride ldc, col<N)
template<int BN, int EPI>
__global__ __launch_bounds__(256) void gemm2(
    const bf16* __restrict__ A, const bf16* __restrict__ B,
    int M, int N, int K, int ldc, const float* __restrict__ bias,
    float* __restrict__ outF, bf16* __restrict__ outB)
{
  constexpr int WN = (BN == 128) ? 64 : 32;   // per-wave N extent
  constexpr int NI = WN / 16;
  constexpr int NB = BN / 32;                 // Bs stage insts per wave
  __shared__ alignas(16) bf16 As[128 * 64];
  __shared__ alignas(16) bf16 Bs[BN * 64];
  const int tid = threadIdx.x;
  const int lane = tid & 63, wave = tid >> 6;
  const int wr = wave >> 1, wc = wave & 1;
  const int lrow = lane & 15, lgrp = lane >> 4;
  const int row0 = blockIdx.x * 128, col0 = blockIdx.y * BN;

  f32x4 acc[4][NI] = {};
  const bf16* Agb = A + (size_t)row0 * K;
  const bf16* Bgb = B + (size_t)col0 * K;
  const int srow = lane >> 3;                 // lane's row within 8-row stripe
  const int schunk = lane & 7;

  const int nk = K >> 6;
  for (int kt = 0; kt < nk; ++kt) {
    const bf16* Ag = Agb + kt * 64;
    const bf16* Bg = Bgb + kt * 64;
    #pragma unroll
    for (int i = 0; i < 4; ++i) {
      int rr = (wave * 4 + i) * 8 + srow;
      int g = schunk ^ (rr & 7);
      gll16(Ag + (size_t)rr * K + g * 8, As + (wave * 4 + i) * 512);
    }
    #pragma unroll
    for (int i = 0; i < NB; ++i) {
      int rr = (wave * NB + i) * 8 + srow;
      int g = schunk ^ (rr & 7);
      gll16(Bg + (size_t)rr * K + g * 8, Bs + (wave * NB + i) * 512);
    }
    __syncthreads();
    #pragma unroll
    for (int kk = 0; kk < 2; ++kk) {
      bf16x8 af[4], bfr[NI];
      #pragma unroll
      for (int mi = 0; mi < 4; ++mi) {
        int r = wr * 64 + mi * 16 + lrow;
        af[mi] = *(const bf16x8*)(As + r * 64 + (((kk * 4 + lgrp) ^ (r & 7)) << 3));
      }
      #pragma unroll
      for (int ni = 0; ni < NI; ++ni) {
        int r = wc * WN + ni * 16 + lrow;
        bfr[ni] = *(const bf16x8*)(Bs + r * 64 + (((kk * 4 + lgrp) ^ (r & 7)) << 3));
      }
      #pragma unroll
      for (int mi = 0; mi < 4; ++mi)
        #pragma unroll
        for (int ni = 0; ni < NI; ++ni)
          acc[mi][ni] = mfma_bf16(af[mi], bfr[ni], acc[mi][ni]);
    }
    __syncthreads();
  }

  // epilogue: C frag layout col = lane&15, row = (lane>>4)*4 + j
  #pragma unroll
  for (int ni = 0; ni < NI; ++ni) {
    const int col = col0 + wc * WN + ni * 16 + lrow;
    float bs = 0.0f;
    if (EPI != 1) {
      if (EPI == 5) bs = (col < N) ? bias[col] : 0.0f;
      else          bs = bias[col];
    }
    #pragma unroll
    for (int mi = 0; mi < 4; ++mi) {
      const int rbase = row0 + wr * 64 + mi * 16 + (lgrp << 2);
      #pragma unroll
      for (int j = 0; j < 4; ++j) {
        const int t = rbase + j;
        if (EPI == 1) {
          float val = acc[mi][ni][j] + bias[t];
          if (t < 768) val *= 0.125f;
          outB[(size_t)t * ldc + col] = (bf16)val;
        } else {
          if (t >= M) continue;
          float val = acc[mi][ni][j] + bs;
          if (EPI == 0) {
            int b = t / 196, p = t - b * 196;
            outF[((size_t)(b * 197 + 1 + p)) * 768 + col] = val;
          } else if (EPI == 2) {
            outF[(size_t)t * 768 + col] += val;
          } else if (EPI == 3) {
            outB[(size_t)t * 3072 + col] = (bf16)(0.5f * val * (1.0f + erff(val * 0.70710678118654752f)));
          } else if (EPI == 4) {
            outB[(size_t)t * 768 + col] = (bf16)tanhf(val);
          } else {
            if (col < N) outF[(size_t)t * ldc + col] = val;
          }
        }
      }
    }
  }
}

// ---------------- attention: one block per (b, head), 8 waves ----------------
// Ct: QKV^T [2304][6400] bf16, cols = b*200 + l (rows n = comp*768 + d*12 + h; Q pre-scaled 1/8).
// O: [6304][768] bf16 (t = b*197 + l).
__global__ __launch_bounds__(512) void attn_k(const bf16* __restrict__ Ct, bf16* __restrict__ O) {
  __shared__ alignas(16) bf16 Ks[208 * 64];       // [l][d] XOR-swizzled
  __shared__ alignas(16) bf16 Qs[208 * 64];       // [l][d] XOR-swizzled
  __shared__ alignas(16) bf16 Vs[64 * 232];       // [d][l] pad 232, cols 197..231 zeroed
  __shared__ alignas(16) bf16 Ps[8][16 * 232];    // per-wave P tile
  const int bh = blockIdx.x;
  const int b = bh / 12, hh = bh - b * 12;
  const int tid = threadIdx.x, lane = tid & 63, wave = tid >> 6;
  const int lrow = lane & 15, lgrp = lane >> 4;
  const size_t tc0 = (size_t)b * 200;

  // stage Q,K,V: 64 d-rows x 25 chunks of 8 tokens, 16B-aligned vector reads
  for (int task = tid; task < 1600; task += 512) {
    int d = task / 25, lc = task - d * 25;
    int l0 = lc * 8;
    const size_t cb = tc0 + l0;
    bf16x8 qv = *(const bf16x8*)(Ct + ((size_t)(d * 12 + hh)) * 6400 + cb);
    bf16x8 kv = *(const bf16x8*)(Ct + ((size_t)(768 + d * 12 + hh)) * 6400 + cb);
    bf16x8 vv = *(const bf16x8*)(Ct + ((size_t)(1536 + d * 12 + hh)) * 6400 + cb);
    #pragma unroll
    for (int e = 0; e < 8; ++e) {
      int l = l0 + e;
      int sw = ((((d >> 3) ^ (l & 7)) << 3) | (d & 7));
      Ks[l * 64 + sw] = kv[e];
      Qs[l * 64 + sw] = qv[e];
    }
    *(bf16x8*)(Vs + d * 232 + l0) = vv;
  }
  for (int q = tid; q < 64 * 35; q += 512) {      // zero V cols 197..231
    int d = q / 35, c = 197 + (q - d * 35);
    Vs[d * 232 + c] = (bf16)0.0f;
  }
  __syncthreads();

  for (int rt = wave; rt < 13; rt += 8) {
    const int r = rt * 16 + lrow;
    bf16x8 a0 = *(const bf16x8*)(Qs + r * 64 + ((lgrp ^ (r & 7)) << 3));
    bf16x8 a1 = *(const bf16x8*)(Qs + r * 64 + (((4 + lgrp) ^ (r & 7)) << 3));
    f32x4 sacc[13];
    #pragma unroll
    for (int ct = 0; ct < 13; ++ct) {
      const int kr = ct * 16 + lrow;
      bf16x8 b0 = *(const bf16x8*)(Ks + kr * 64 + ((lgrp ^ (kr & 7)) << 3));
      bf16x8 b1 = *(const bf16x8*)(Ks + kr * 64 + (((4 + lgrp) ^ (kr & 7)) << 3));
      f32x4 s = {};
      s = mfma_bf16(a0, b0, s);
      s = mfma_bf16(a1, b1, s);
      sacc[ct] = s;
    }
    bf16* Pw = Ps[wave];
    float inv4[4];
    #pragma unroll
    for (int j = 0; j < 4; ++j) {
      const int prow = (lgrp << 2) + j;
      float mx = -3.0e38f;
      #pragma unroll
      for (int ct = 0; ct < 13; ++ct) {
        int c = ct * 16 + lrow;
        if (c < 197) mx = fmaxf(mx, sacc[ct][j]);
      }
      #pragma unroll
      for (int o = 1; o < 16; o <<= 1) mx = fmaxf(mx, __shfl_xor(mx, o));
      float sum = 0.0f;
      #pragma unroll
      for (int ct = 0; ct < 13; ++ct) {
        int c = ct * 16 + lrow;
        float p = (c < 197) ? __expf(sacc[ct][j] - mx) : 0.0f;
        sum += p;
        Pw[prow * 232 + c] = (bf16)p;
      }
      #pragma unroll
      for (int o = 1; o < 16; o <<= 1) sum += __shfl_xor(sum, o);
      inv4[j] = 1.0f / sum;
      Pw[prow * 232 + 208 + lrow] = (bf16)0.0f;   // zero P cols 208..223
    }
    f32x4 oacc[4] = {};
    #pragma unroll
    for (int mc = 0; mc < 7; ++mc) {              // K-dim 224
      bf16x8 pa = *(const bf16x8*)(Pw + lrow * 232 + mc * 32 + (lgrp << 3));
      #pragma unroll
      for (int n2 = 0; n2 < 4; ++n2) {
        bf16x8 vb = *(const bf16x8*)(Vs + (n2 * 16 + lrow) * 232 + mc * 32 + (lgrp << 3));
        oacc[n2] = mfma_bf16(pa, vb, oacc[n2]);
      }
    }
    #pragma unroll
    for (int n2 = 0; n2 < 4; ++n2) {
      const int d = n2 * 16 + lrow;
      #pragma unroll
      for (int j = 0; j < 4; ++j) {
        const int qrow = rt * 16 + (lgrp << 2) + j;
        if (qrow < 197)
          O[((size_t)b * 197 + qrow) * 768 + hh * 64 + d] = (bf16)(oacc[n2][j] * inv4[j]);
      }
    }
  }
}

// ---------------- driver ----------------

extern "C" void kernel_launch(void* const* d_in, const int* in_sizes, int n_in,
                              void* d_out, int out_size, void* d_ws, size_t ws_size,
                              hipStream_t stream) {
  const float* x      = (const float*)d_in[0];
  const float* w_proj = (const float*)d_in[1];
  const float* b_proj = (const float*)d_in[2];
  const float* cls    = (const float*)d_in[3];
  const float* ln1g   = (const float*)d_in[4];
  const float* ln1b   = (const float*)d_in[5];
  const float* w_qkv  = (const float*)d_in[6];
  const float* b_qkv  = (const float*)d_in[7];
  const float* w_o    = (const float*)d_in[8];
  const float* b_o    = (const float*)d_in[9];
  const float* ln2g   = (const float*)d_in[10];
  const float* ln2b   = (const float*)d_in[11];
  const float* w_fc1  = (const float*)d_in[12];
  const float* b_fc1  = (const float*)d_in[13];
  const float* w_fc2  = (const float*)d_in[14];
  const float* b_fc2  = (const float*)d_in[15];
  const float* lnfg   = (const float*)d_in[16];
  const float* lnfb   = (const float*)d_in[17];
  const float* w_h    = (const float*)d_in[18];
  const float* b_h    = (const float*)d_in[19];
  const float* w_c    = (const float*)d_in[20];
  const float* b_c    = (const float*)d_in[21];
  float* out = (float*)d_out;

  uint8_t* ws = (uint8_t*)d_ws;
  size_t off = 0;
  auto alloc = [&](size_t bytes) -> void* {
    void* p = ws + off; off += (bytes + 255) & ~(size_t)255; return p;
  };
  float* h    = (float*)alloc(6400ull * 768 * 4);   // residual fp32 (t = b*197+l)
  bf16*  ybf  = (bf16*) alloc(6400ull * 768 * 2);   // LN out bf16 (plain OR b*200+l padded)
  bf16*  ct   = (bf16*) alloc(2304ull * 6400 * 2);  // QKV^T, cols b*200+l
  bf16*  ob   = (bf16*) alloc(6400ull * 768 * 2);   // attention out bf16
  bf16*  f1   = (bf16*) alloc(6400ull * 3072 * 2);  // FC1 out bf16
  float* pos  = (float*)alloc(197ull * 768 * 4);
  bf16* wprojB = (bf16*)alloc(768ull * 768 * 2);
  bf16* wqkvB  = (bf16*)alloc(2304ull * 768 * 2);
  bf16* woB    = (bf16*)alloc(768ull * 768 * 2);
  bf16* wfc1B  = (bf16*)alloc(3072ull * 768 * 2);
  bf16* wfc2B  = (bf16*)alloc(768ull * 3072 * 2);
  bf16* whB    = (bf16*)alloc(768ull * 768 * 2);
  bf16* wcB    = (bf16*)alloc(1024ull * 768 * 2);   // rows 1000..1023 poison (finite)
  bf16* repB   = (bf16*)alloc(128ull * 768 * 2);    // rows 32..127 poison
  bf16* hidB   = (bf16*)alloc(128ull * 768 * 2);
  bf16* patches = f1;   // alias: patches dead before FC1 first writes f1

  f2b_k<<<(768 * 768 + 255) / 256, 256, 0, stream>>>(w_proj, wprojB, 768 * 768);
  f2b_k<<<(2304 * 768 + 255) / 256, 256, 0, stream>>>(w_qkv, wqkvB, 2304 * 768);
  f2b_k<<<(768 * 768 + 255) / 256, 256, 0, stream>>>(w_o, woB, 768 * 768);
  f2b_k<<<(3072 * 768 + 255) / 256, 256, 0, stream>>>(w_fc1, wfc1B, 3072 * 768);
  f2b_k<<<(768 * 3072 + 255) / 256, 256, 0, stream>>>(w_fc2, wfc2B, 768 * 3072);
  f2b_k<<<(768 * 768 + 255) / 256, 256, 0, stream>>>(w_h, whB, 768 * 768);
  f2b_k<<<(1000 * 768 + 255) / 256, 256, 0, stream>>>(w_c, wcB, 1000 * 768);
  posenc_k<<<197, 256, 0, stream>>>(pos);
  patchify_k<<<6272 * 768 / 256, 256, 0, stream>>>(x, patches);
  gemm2<64, 0><<<dim3(49, 12), 256, 0, stream>>>(patches, wprojB, 6272, 768, 768, 768, b_proj, h, nullptr);
  combine_k<<<6304 * 768 / 256, 256, 0, stream>>>(h, pos, cls);

  for (int layer = 0; layer < 12; ++layer) {
    ln4_k<1><<<1576, 256, 0, stream>>>(h, ln1g, ln1b, ybf, 6304, 768);
    // QKV^T: A = w_qkv [2304][768], B = ybf(padded rows) -> Ct [2304][6400]
    gemm2<128, 1><<<dim3(18, 50), 256, 0, stream>>>(wqkvB, ybf, 2304, 6400, 768, 6400, b_qkv, nullptr, ct);
    attn_k<<<384, 512, 0, stream>>>(ct, ob);
    gemm2<64, 2><<<dim3(50, 12), 256, 0, stream>>>(ob, woB, 6304, 768, 768, 768, b_o, h, nullptr);
    ln4_k<0><<<1576, 256, 0, stream>>>(h, ln2g, ln2b, ybf, 6304, 768);
    gemm2<128, 3><<<dim3(50, 24), 256, 0, stream>>>(ybf, wfc1B, 6304, 3072, 768, 3072, b_fc1, nullptr, f1);
    gemm2<64, 2><<<dim3(50, 12), 256, 0, stream>>>(f1, wfc2B, 6304, 768, 3072, 768, b_fc2, h, nullptr);
  }

  ln4_k<0><<<8, 256, 0, stream>>>(h, lnfg, lnfb, repB, 32, 197 * 768);
  gemm2<64, 4><<<dim3(1, 12), 256, 0, stream>>>(repB, whB, 32, 768, 768, 768, b_h, nullptr, hidB);
  gemm2<64, 5><<<dim3(1, 16), 256, 0, stream>>>(hidB, wcB, 32, 1000, 768, 1000, b_c, out, nullptr);
}